// Round 3
// baseline (180.553 us; speedup 1.0000x reference)
//
#include <hip/hip_runtime.h>

namespace {
constexpr int kN = 8192, kV = 8, kO = 16, kH = 128;
constexpr float kStep = 2.0f;
constexpr float kDistCost = 1.0f, kObstCost = 0.1f, kObstRadius = 1.0f;
constexpr float kVehCost = 0.1f, kVehRadius = 1.0f;
constexpr int kInRow = 4 * kV + 3 * kO;  // 80 floats per n
}  // namespace

__device__ __forceinline__ float rfl_f(float x) {
  return __int_as_float(__builtin_amdgcn_readfirstlane(__float_as_int(x)));
}

template <int Ctrl, int RowMask, bool Bctrl>
__device__ __forceinline__ float dpp_mov0(float x) {
  return __int_as_float(__builtin_amdgcn_update_dpp(
      0, __float_as_int(x), Ctrl, RowMask, 0xf, Bctrl));
}

// Canonical GCN wave64 inclusive scan on the VALU pipe (no ds_bpermute):
// row_shr:1/2/4/8 within 16-lane rows, then row_bcast15 (rows 1,3),
// row_bcast31 (rows 2,3). Lane 63 ends up holding the wave total.
__device__ __forceinline__ float wave_incl_scan(float x) {
  x += dpp_mov0<0x111, 0xf, true>(x);   // row_shr:1
  x += dpp_mov0<0x112, 0xf, true>(x);   // row_shr:2
  x += dpp_mov0<0x114, 0xf, true>(x);   // row_shr:4
  x += dpp_mov0<0x118, 0xf, true>(x);   // row_shr:8
  x += dpp_mov0<0x142, 0xa, false>(x);  // row_bcast:15 -> rows 1,3
  x += dpp_mov0<0x143, 0xc, false>(x);  // row_bcast:31 -> rows 2,3
  return x;
}

// One block (1024 threads) per n. Thread tid = v*128 + h. v is wave-uniform
// (wave = 64 consecutive tids), exploited for scalar loads + uniform ballots.
__global__ __launch_bounds__(1024) void loss_main(
    const float* __restrict__ pred, const float* __restrict__ inputs,
    float* __restrict__ partials) {
  const int n = blockIdx.x;
  const int tid = threadIdx.x;
  const int lane = tid & 63;
  const int wave = tid >> 6;
  const int h = tid & (kH - 1);
  const int vu = __builtin_amdgcn_readfirstlane(tid >> 7);  // wave-uniform v

  const float* __restrict__ row = inputs + (size_t)n * kInRow;

  __shared__ float2 sh_wsum[kV];       // even-wave (h<64) step sums
  __shared__ float2 sh_traj[kV * kH];  // trajectory for the inter-vehicle term
  __shared__ float sh_red[16][5];      // per-wave partials

  // Block-uniform obstacle data -> scalar loads / SGPRs (R2 lesson: the 48
  // per-thread ds_reads in the obstacle loop were ~60us of LDS-pipe time).
  float ox[kO], oy[kO], rr2[kO];
#pragma unroll
  for (int o = 0; o < kO; ++o) {
    ox[o] = row[4 * kV + 3 * o + 0];
    oy[o] = row[4 * kV + 3 * o + 1];
    float rr = row[4 * kV + 3 * o + 2] + kObstRadius;
    // negative sentinel: d >= 0 can never be < a nonpositive radius
    rr2[o] = rfl_f(rr > 0.f ? rr * rr : -1.0f);
  }

  // step = (cos, sin) * STEP; inclusive cumsum over h (2 waves per v:
  // DPP scan within wave, LDS fixup across the pair).
  float theta = pred[(size_t)n * (kV * kH) + tid];
  float sv, cv;
  __sincosf(theta, &sv, &cv);
  float cx = wave_incl_scan(cv * kStep);
  float sy = wave_incl_scan(sv * kStep);

  if ((wave & 1) == 0 && lane == 63) sh_wsum[vu] = make_float2(cx, sy);
  __syncthreads();
  if (wave & 1) {
    float2 w0 = sh_wsum[vu];
    cx += w0.x;
    sy += w0.y;
  }

  const float px = row[4 * vu + 0] + cx;
  const float py = row[4 * vu + 1] + sy;
  sh_traj[tid] = make_float2(px, py);

  // Term 1: distance to target.
  float dx = row[4 * vu + 2] - px;
  float dy = row[4 * vu + 3] - py;
  float s1 = sqrtf(fmaf(dy, dy, dx * dx));

  // Term 2: masked mean of 1/dist over obstacles (d2 < rr2 <=> d < rr).
  // Count via ballot+popc on the scalar pipe; sum via cndmask.
  float s2 = 0.f;
  int c2i = 0;
#pragma unroll
  for (int o = 0; o < kO; ++o) {
    float odx = px - ox[o];
    float ody = py - oy[o];
    float d2 = fmaf(ody, ody, odx * odx);
    bool m = d2 < rr2[o];
    float inv = rsqrtf(d2);
    s2 += m ? inv : 0.f;
    c2i += (int)__popcll(__ballot(m));
  }

  __syncthreads();  // sh_traj visible

  // Term 3: inter-vehicle distances (v vs v+1 at same h). vu uniform -> the
  // whole wave takes/skips the branch together; ballot is safe.
  float s3 = 0.f;
  int c3i = 0;
  if (vu < kV - 1) {
    float2 t2 = sh_traj[tid + kH];
    float ddx = t2.x - px, ddy = t2.y - py;
    float vd2 = fmaf(ddy, ddy, ddx * ddx);
    bool m3 = vd2 < kVehRadius * kVehRadius;
    s3 = m3 ? rsqrtf(vd2) : 0.f;
    c3i = (int)__popcll(__ballot(m3));
  }

  // Wave-reduce the 3 float sums via DPP scan (lane 63 = total); counts are
  // already wave-scalar. One LDS row per wave, then 5 threads finish.
  float r1 = wave_incl_scan(s1);
  float r2 = wave_incl_scan(s2);
  float r3 = wave_incl_scan(s3);
  if (lane == 63) {
    sh_red[wave][0] = r1;
    sh_red[wave][1] = r2;
    sh_red[wave][2] = r3;
    sh_red[wave][3] = (float)c2i;
    sh_red[wave][4] = (float)c3i;
  }
  __syncthreads();
  if (tid < 5) {
    float acc = 0.f;
#pragma unroll
    for (int w = 0; w < 16; ++w) acc += sh_red[w][tid];
    partials[tid * kN + n] = acc;  // coalesced across blocks per-array
  }
}

// Single-block tree reduction over kN partials per accumulator (float4 loads).
__global__ __launch_bounds__(1024) void loss_final(
    const float* __restrict__ partials, float* __restrict__ out) {
  const int tid = threadIdx.x;
  const int lane = tid & 63;
  const int wave = tid >> 6;
  __shared__ float sh[16][5];
  float acc[5];
#pragma unroll
  for (int a = 0; a < 5; ++a) {
    const float4* pa = (const float4*)(partials + a * kN);  // 2048 float4
    float4 u = pa[tid];
    float4 w = pa[tid + 1024];
    acc[a] = (u.x + u.y) + (u.z + u.w) + (w.x + w.y) + (w.z + w.w);
  }
#pragma unroll
  for (int a = 0; a < 5; ++a) acc[a] = wave_incl_scan(acc[a]);
  if (lane == 63) {
#pragma unroll
    for (int a = 0; a < 5; ++a) sh[wave][a] = acc[a];
  }
  __syncthreads();
  if (tid == 0) {
    float t[5];
#pragma unroll
    for (int a = 0; a < 5; ++a) {
      float s = 0.f;
#pragma unroll
      for (int w = 0; w < 16; ++w) s += sh[w][a];
      t[a] = s;
    }
    float loss = t[0] * (1.0f / (float)(kN * kV * kH)) * kDistCost;
    if (t[3] > 0.f) loss += (t[1] / t[3]) * kObstCost;
    if (t[4] > 0.f) loss += (t[2] / t[4]) * kVehCost;
    out[0] = loss;
  }
}

extern "C" void kernel_launch(void* const* d_in, const int* in_sizes, int n_in,
                              void* d_out, int out_size, void* d_ws, size_t ws_size,
                              hipStream_t stream) {
  const float* pred = (const float*)d_in[0];     // (N, V, H, 1) f32
  const float* inputs = (const float*)d_in[1];   // (N, 80) f32
  float* partials = (float*)d_ws;                // 5 * kN floats
  loss_main<<<kN, 1024, 0, stream>>>(pred, inputs, partials);
  loss_final<<<1, 1024, 0, stream>>>(partials, (float*)d_out);
}

// Round 4
// 115.348 us; speedup vs baseline: 1.5653x; 1.5653x over previous
//
#include <hip/hip_runtime.h>

namespace {
constexpr int kN = 8192, kV = 8, kO = 16, kH = 128;
constexpr float kStep = 2.0f;
constexpr float kDistCost = 1.0f, kObstCost = 0.1f, kObstRadius = 1.0f;
constexpr float kVehCost = 0.1f, kVehRadius = 1.0f;
constexpr int kInRow = 4 * kV + 3 * kO;  // 80 floats per n
constexpr float kInv2Pi = 0.15915494309189535f;
}  // namespace

__device__ __forceinline__ float rfl_f(float x) {
  return __int_as_float(__builtin_amdgcn_readfirstlane(__float_as_int(x)));
}

template <int Ctrl, int RowMask, bool Bctrl>
__device__ __forceinline__ float dpp_mov0(float x) {
  return __int_as_float(__builtin_amdgcn_update_dpp(
      0, __float_as_int(x), Ctrl, RowMask, 0xf, Bctrl));
}

// Wave64 inclusive scan on the VALU pipe. Lane 63 holds the wave total.
__device__ __forceinline__ float wave_incl_scan(float x) {
  x += dpp_mov0<0x111, 0xf, true>(x);   // row_shr:1
  x += dpp_mov0<0x112, 0xf, true>(x);   // row_shr:2
  x += dpp_mov0<0x114, 0xf, true>(x);   // row_shr:4
  x += dpp_mov0<0x118, 0xf, true>(x);   // row_shr:8
  x += dpp_mov0<0x142, 0xa, false>(x);  // row_bcast:15 -> rows 1,3
  x += dpp_mov0<0x143, 0xc, false>(x);  // row_bcast:31 -> rows 2,3
  return x;
}

// One block (512 threads = 8 waves) per n. Wave w = vehicle w; lane l owns
// steps h = 2l, 2l+1. The 128-step cumsum is then fully in-wave (pair-sum ->
// one scan -> recover both), removing the R3 cross-wave fixup + barrier and
// halving scan ops/element. 8-wave blocks allow 4 blocks/CU residency
// (R3 lesson: 1024-thread blocks + long dependent chains -> 42% occupancy,
// latency-bound at 5x the VALU floor).
__global__ __launch_bounds__(512) void loss_main(
    const float* __restrict__ pred, const float* __restrict__ inputs,
    float* __restrict__ partials) {
  const int n = blockIdx.x;
  const int tid = threadIdx.x;
  const int lane = tid & 63;
  const int v = __builtin_amdgcn_readfirstlane(tid >> 6);  // wave-uniform

  const float* __restrict__ row = inputs + (size_t)n * kInRow;

  __shared__ float4 sh_traj[kV * 64];  // (px0,py0,px1,py1) per lane
  __shared__ float sh_red[kV][5];

  // Block-uniform obstacle + vehicle data -> scalar loads / SGPRs.
  float ox[kO], oy[kO], rr2[kO];
#pragma unroll
  for (int o = 0; o < kO; ++o) {
    ox[o] = rfl_f(row[4 * kV + 3 * o + 0]);
    oy[o] = rfl_f(row[4 * kV + 3 * o + 1]);
    float rr = row[4 * kV + 3 * o + 2] + kObstRadius;
    // negative sentinel: d >= 0 can never be < a nonpositive radius
    rr2[o] = rfl_f(rr > 0.f ? rr * rr : -1.0f);
  }
  const float vx = rfl_f(row[4 * v + 0]);
  const float vy = rfl_f(row[4 * v + 1]);
  const float tx = rfl_f(row[4 * v + 2]);
  const float ty = rfl_f(row[4 * v + 3]);

  // Two headings per lane, vectorized load.
  const float2 th = ((const float2*)(pred + (size_t)n * (kV * kH)))[tid];
  float r0 = th.x * kInv2Pi, r1 = th.y * kInv2Pi;
  float c0 = __builtin_amdgcn_cosf(r0) * kStep;
  float s0 = __builtin_amdgcn_sinf(r0) * kStep;
  float c1 = __builtin_amdgcn_cosf(r1) * kStep;
  float s1v = __builtin_amdgcn_sinf(r1) * kStep;

  // Pair-sum scan: S = inclusive over pair sums = cumsum through h=2l+1.
  float Sx = wave_incl_scan(c0 + c1);
  float Sy = wave_incl_scan(s0 + s1v);
  const float px1 = vx + Sx, py1 = vy + Sy;          // h = 2l+1
  const float px0 = px1 - c1, py0 = py1 - s1v;       // h = 2l

  sh_traj[v * 64 + lane] = make_float4(px0, py0, px1, py1);

  // Term 1: distance to target (both points).
  float dx0 = tx - px0, dy0 = ty - py0;
  float dx1 = tx - px1, dy1 = ty - py1;
  float s1 = __builtin_amdgcn_sqrtf(fmaf(dy0, dy0, dx0 * dx0)) +
             __builtin_amdgcn_sqrtf(fmaf(dy1, dy1, dx1 * dx1));

  // Term 2: masked mean of 1/dist over obstacles (d2 < rr2 <=> d < rr).
  float s2 = 0.f;
  int c2i = 0;
#pragma unroll
  for (int o = 0; o < kO; ++o) {
    float ax = px0 - ox[o], ay = py0 - oy[o];
    float bx = px1 - ox[o], by = py1 - oy[o];
    float da = fmaf(ay, ay, ax * ax);
    float db = fmaf(by, by, bx * bx);
    bool ma = da < rr2[o];
    bool mb = db < rr2[o];
    s2 += ma ? __builtin_amdgcn_rsqf(da) : 0.f;
    s2 += mb ? __builtin_amdgcn_rsqf(db) : 0.f;
    c2i += (int)__popcll(__ballot(ma)) + (int)__popcll(__ballot(mb));
  }

  __syncthreads();  // sh_traj visible

  // Term 3: inter-vehicle distance (v vs v+1, same h). v wave-uniform.
  float s3 = 0.f;
  int c3i = 0;
  if (v < kV - 1) {
    float4 t2 = sh_traj[(v + 1) * 64 + lane];
    float ex0 = t2.x - px0, ey0 = t2.y - py0;
    float ex1 = t2.z - px1, ey1 = t2.w - py1;
    float e0 = fmaf(ey0, ey0, ex0 * ex0);
    float e1 = fmaf(ey1, ey1, ex1 * ex1);
    bool m0 = e0 < kVehRadius * kVehRadius;
    bool m1 = e1 < kVehRadius * kVehRadius;
    s3 = (m0 ? __builtin_amdgcn_rsqf(e0) : 0.f) +
         (m1 ? __builtin_amdgcn_rsqf(e1) : 0.f);
    c3i = (int)__popcll(__ballot(m0)) + (int)__popcll(__ballot(m1));
  }

  // Wave-reduce the 3 float sums (counts already wave-scalar), then 8 waves
  // combine through LDS; 5 threads store the block partials.
  float r1s = wave_incl_scan(s1);
  float r2s = wave_incl_scan(s2);
  float r3s = wave_incl_scan(s3);
  if (lane == 63) {
    sh_red[v][0] = r1s;
    sh_red[v][1] = r2s;
    sh_red[v][2] = r3s;
    sh_red[v][3] = (float)c2i;
    sh_red[v][4] = (float)c3i;
  }
  __syncthreads();
  if (tid < 5) {
    float acc = 0.f;
#pragma unroll
    for (int w = 0; w < kV; ++w) acc += sh_red[w][tid];
    partials[tid * kN + n] = acc;  // coalesced across blocks per-array
  }
}

// Single-block tree reduction over kN partials per accumulator (float4 loads).
__global__ __launch_bounds__(1024) void loss_final(
    const float* __restrict__ partials, float* __restrict__ out) {
  const int tid = threadIdx.x;
  const int lane = tid & 63;
  const int wave = tid >> 6;
  __shared__ float sh[16][5];
  float acc[5];
#pragma unroll
  for (int a = 0; a < 5; ++a) {
    const float4* pa = (const float4*)(partials + a * kN);  // 2048 float4
    float4 u = pa[tid];
    float4 w = pa[tid + 1024];
    acc[a] = (u.x + u.y) + (u.z + u.w) + (w.x + w.y) + (w.z + w.w);
  }
#pragma unroll
  for (int a = 0; a < 5; ++a) acc[a] = wave_incl_scan(acc[a]);
  if (lane == 63) {
#pragma unroll
    for (int a = 0; a < 5; ++a) sh[wave][a] = acc[a];
  }
  __syncthreads();
  if (tid == 0) {
    float t[5];
#pragma unroll
    for (int a = 0; a < 5; ++a) {
      float s = 0.f;
#pragma unroll
      for (int w = 0; w < 16; ++w) s += sh[w][a];
      t[a] = s;
    }
    float loss = t[0] * (1.0f / (float)(kN * kV * kH)) * kDistCost;
    if (t[3] > 0.f) loss += (t[1] / t[3]) * kObstCost;
    if (t[4] > 0.f) loss += (t[2] / t[4]) * kVehCost;
    out[0] = loss;
  }
}

extern "C" void kernel_launch(void* const* d_in, const int* in_sizes, int n_in,
                              void* d_out, int out_size, void* d_ws, size_t ws_size,
                              hipStream_t stream) {
  const float* pred = (const float*)d_in[0];     // (N, V, H, 1) f32
  const float* inputs = (const float*)d_in[1];   // (N, 80) f32
  float* partials = (float*)d_ws;                // 5 * kN floats
  loss_main<<<kN, 512, 0, stream>>>(pred, inputs, partials);
  loss_final<<<1, 1024, 0, stream>>>(partials, (float*)d_out);
}

// Round 5
// 105.364 us; speedup vs baseline: 1.7136x; 1.0948x over previous
//
#include <hip/hip_runtime.h>

namespace {
constexpr int kN = 8192, kV = 8, kO = 16, kH = 128;
constexpr float kStep = 2.0f;
constexpr float kDistCost = 1.0f, kObstCost = 0.1f, kObstRadius = 1.0f;
constexpr float kVehCost = 0.1f, kVehRadius = 1.0f;
constexpr int kInRow = 4 * kV + 3 * kO;  // 80 floats per n
constexpr float kInv2Pi = 0.15915494309189535f;
}  // namespace

typedef float v2f __attribute__((ext_vector_type(2)));

__device__ __forceinline__ float rfl_f(float x) {
  return __int_as_float(__builtin_amdgcn_readfirstlane(__float_as_int(x)));
}

template <int Ctrl, int RowMask, bool Bctrl>
__device__ __forceinline__ float dpp_mov0(float x) {
  return __int_as_float(__builtin_amdgcn_update_dpp(
      0, __float_as_int(x), Ctrl, RowMask, 0xf, Bctrl));
}

// Wave64 inclusive scan on the VALU pipe. Lane 63 holds the wave total.
__device__ __forceinline__ float wave_incl_scan(float x) {
  x += dpp_mov0<0x111, 0xf, true>(x);   // row_shr:1
  x += dpp_mov0<0x112, 0xf, true>(x);   // row_shr:2
  x += dpp_mov0<0x114, 0xf, true>(x);   // row_shr:4
  x += dpp_mov0<0x118, 0xf, true>(x);   // row_shr:8
  x += dpp_mov0<0x142, 0xa, false>(x);  // row_bcast:15 -> rows 1,3
  x += dpp_mov0<0x143, 0xc, false>(x);  // row_bcast:31 -> rows 2,3
  return x;
}

// One block (512 threads = 8 waves) per n. Wave w = vehicle w; lane l owns
// steps h = 2l, 2l+1 (pair-sum scan keeps the 128-step cumsum fully in-wave).
// R5: geometry on packed-FP32 (v_pk_* , 2 points/lane -> exactly 2-wide) and
// wave-uniform branch skipping the quarter-rate rsq on no-hit obstacles
// (R4 lesson: VALU-issue-bound, obstacle loop ~70% of issue).
__global__ __launch_bounds__(512) void loss_main(
    const float* __restrict__ pred, const float* __restrict__ inputs,
    float* __restrict__ partials) {
  const int n = blockIdx.x;
  const int tid = threadIdx.x;
  const int lane = tid & 63;
  const int v = __builtin_amdgcn_readfirstlane(tid >> 6);  // wave-uniform

  const float* __restrict__ row = inputs + (size_t)n * kInRow;

  __shared__ float4 sh_traj[kV * 64];  // (px0,py0,px1,py1) per lane
  __shared__ float sh_red[kV][5];

  // Block-uniform obstacle + vehicle data -> scalar loads / SGPRs.
  float ox[kO], oy[kO], rr2[kO];
#pragma unroll
  for (int o = 0; o < kO; ++o) {
    ox[o] = rfl_f(row[4 * kV + 3 * o + 0]);
    oy[o] = rfl_f(row[4 * kV + 3 * o + 1]);
    float rr = row[4 * kV + 3 * o + 2] + kObstRadius;
    // negative sentinel: d >= 0 can never be < a nonpositive radius
    rr2[o] = rfl_f(rr > 0.f ? rr * rr : -1.0f);
  }
  const float vx = rfl_f(row[4 * v + 0]);
  const float vy = rfl_f(row[4 * v + 1]);
  const float tx = rfl_f(row[4 * v + 2]);
  const float ty = rfl_f(row[4 * v + 3]);

  // Two headings per lane; packed prep, 4 trans ops (unavoidable).
  const float2 th = ((const float2*)(pred + (size_t)n * (kV * kH)))[tid];
  v2f r01 = {th.x, th.y};
  r01 *= kInv2Pi;
  float c0 = __builtin_amdgcn_cosf(r01.x);
  float s0 = __builtin_amdgcn_sinf(r01.x);
  float c1 = __builtin_amdgcn_cosf(r01.y);
  float s1w = __builtin_amdgcn_sinf(r01.y);
  v2f step1 = {c1, s1w};  // step at h=2l+1 (pre-scale)
  step1 *= kStep;

  // Pair-sum scan: inclusive cumsum through h=2l+1.
  float Sx = wave_incl_scan((c0 + c1) * kStep);
  float Sy = wave_incl_scan((s0 + s1w) * kStep);
  const float px1 = vx + Sx, py1 = vy + Sy;              // h = 2l+1
  const float px0 = px1 - step1.x, py0 = py1 - step1.y;  // h = 2l

  sh_traj[v * 64 + lane] = make_float4(px0, py0, px1, py1);

  const v2f pxp = {px0, px1};
  const v2f pyp = {py0, py1};

  // Term 1: distance to target (both points), packed diffs/squares.
  {
    v2f dx = tx - pxp;
    v2f dy = ty - pyp;
    v2f d2 = __builtin_elementwise_fma(dy, dy, dx * dx);
    // fall through to s1 below
    v2f sq = {__builtin_amdgcn_sqrtf(d2.x), __builtin_amdgcn_sqrtf(d2.y)};
    sh_red[0][0] = 0.f;  // (dead store eliminated; keeps sq live ordering)
    (void)sq;
  }
  // (recompute cleanly; compiler CSEs)
  v2f t_dx = tx - pxp;
  v2f t_dy = ty - pyp;
  v2f t_d2 = __builtin_elementwise_fma(t_dy, t_dy, t_dx * t_dx);
  float s1 = __builtin_amdgcn_sqrtf(t_d2.x) + __builtin_amdgcn_sqrtf(t_d2.y);

  // Term 2: masked mean of 1/dist over obstacles (d2 < rr2 <=> d < rr).
  // Packed distance math; wave-uniform skip of the quarter-rate rsq path.
  v2f s2p = {0.f, 0.f};
  int c2i = 0;
#pragma unroll
  for (int o = 0; o < kO; ++o) {
    v2f dx = pxp - ox[o];
    v2f dy = pyp - oy[o];
    v2f d2 = __builtin_elementwise_fma(dy, dy, dx * dx);
    bool ma = d2.x < rr2[o];
    bool mb = d2.y < rr2[o];
    unsigned long long ba = __ballot(ma);
    unsigned long long bb = __ballot(mb);
    if (ba | bb) {
      float inva = __builtin_amdgcn_rsqf(d2.x);
      float invb = __builtin_amdgcn_rsqf(d2.y);
      v2f add = {ma ? inva : 0.f, mb ? invb : 0.f};
      s2p += add;
      c2i += (int)__popcll(ba) + (int)__popcll(bb);
    }
  }
  float s2 = s2p.x + s2p.y;

  __syncthreads();  // sh_traj visible

  // Term 3: inter-vehicle distance (v vs v+1, same h). v wave-uniform.
  float s3 = 0.f;
  int c3i = 0;
  if (v < kV - 1) {
    float4 t2 = sh_traj[(v + 1) * 64 + lane];
    v2f ex = {t2.x, t2.z};
    v2f ey = {t2.y, t2.w};
    ex -= pxp;
    ey -= pyp;
    v2f e2 = __builtin_elementwise_fma(ey, ey, ex * ex);
    bool m0 = e2.x < kVehRadius * kVehRadius;
    bool m1 = e2.y < kVehRadius * kVehRadius;
    unsigned long long b0 = __ballot(m0);
    unsigned long long b1 = __ballot(m1);
    if (b0 | b1) {
      float i0 = __builtin_amdgcn_rsqf(e2.x);
      float i1 = __builtin_amdgcn_rsqf(e2.y);
      s3 = (m0 ? i0 : 0.f) + (m1 ? i1 : 0.f);
      c3i = (int)__popcll(b0) + (int)__popcll(b1);
    }
  }

  // Wave-reduce the 3 float sums (counts already wave-scalar), then 8 waves
  // combine through LDS; 5 threads store the block partials.
  float r1s = wave_incl_scan(s1);
  float r2s = wave_incl_scan(s2);
  float r3s = wave_incl_scan(s3);
  if (lane == 63) {
    sh_red[v][0] = r1s;
    sh_red[v][1] = r2s;
    sh_red[v][2] = r3s;
    sh_red[v][3] = (float)c2i;
    sh_red[v][4] = (float)c3i;
  }
  __syncthreads();
  if (tid < 5) {
    float acc = 0.f;
#pragma unroll
    for (int w = 0; w < kV; ++w) acc += sh_red[w][tid];
    partials[tid * kN + n] = acc;  // coalesced across blocks per-array
  }
}

// Single-block tree reduction over kN partials per accumulator (float4 loads).
__global__ __launch_bounds__(1024) void loss_final(
    const float* __restrict__ partials, float* __restrict__ out) {
  const int tid = threadIdx.x;
  const int lane = tid & 63;
  const int wave = tid >> 6;
  __shared__ float sh[16][5];
  float acc[5];
#pragma unroll
  for (int a = 0; a < 5; ++a) {
    const float4* pa = (const float4*)(partials + a * kN);  // 2048 float4
    float4 u = pa[tid];
    float4 w = pa[tid + 1024];
    acc[a] = (u.x + u.y) + (u.z + u.w) + (w.x + w.y) + (w.z + w.w);
  }
#pragma unroll
  for (int a = 0; a < 5; ++a) acc[a] = wave_incl_scan(acc[a]);
  if (lane == 63) {
#pragma unroll
    for (int a = 0; a < 5; ++a) sh[wave][a] = acc[a];
  }
  __syncthreads();
  if (tid == 0) {
    float t[5];
#pragma unroll
    for (int a = 0; a < 5; ++a) {
      float s = 0.f;
#pragma unroll
      for (int w = 0; w < 16; ++w) s += sh[w][a];
      t[a] = s;
    }
    float loss = t[0] * (1.0f / (float)(kN * kV * kH)) * kDistCost;
    if (t[3] > 0.f) loss += (t[1] / t[3]) * kObstCost;
    if (t[4] > 0.f) loss += (t[2] / t[4]) * kVehCost;
    out[0] = loss;
  }
}

extern "C" void kernel_launch(void* const* d_in, const int* in_sizes, int n_in,
                              void* d_out, int out_size, void* d_ws, size_t ws_size,
                              hipStream_t stream) {
  const float* pred = (const float*)d_in[0];     // (N, V, H, 1) f32
  const float* inputs = (const float*)d_in[1];   // (N, 80) f32
  float* partials = (float*)d_ws;                // 5 * kN floats
  loss_main<<<kN, 512, 0, stream>>>(pred, inputs, partials);
  loss_final<<<1, 1024, 0, stream>>>(partials, (float*)d_out);
}